// Round 3
// baseline (97.214 us; speedup 1.0000x reference)
//
#include <hip/hip_runtime.h>
#include <math.h>

// Layout: 196 real float4-chunks of 4 pixels each, padded to 256 with zero
// table records. Table in d_ws, SoA, slot-major:
//   tab4[0..255]            = alpha (per pixel)
//   tab4[256..511]          = beta
//   tab4[(2+cl)*256 + c]    = w[cl] permuted to pixel order, cl in [0,10)
#define NCH 256

struct c2 { float re, im; };
__device__ inline c2 cmul(c2 a, c2 b){ return {a.re*b.re - a.im*b.im, a.re*b.im + a.im*b.re}; }
__device__ inline c2 cadd(c2 a, c2 b){ return {a.re+b.re, a.im+b.im}; }

__device__ inline void su2_alpha_beta(const float* __restrict__ params, float* Aq, float* Bq) {
    #pragma unroll
    for (int q = 0; q < 4; ++q) {
        c2 m00 = {1.f, 0.f}, m01 = {0.f, 0.f}, m10 = {0.f, 0.f}, m11 = {1.f, 0.f};
        #pragma unroll
        for (int d = 0; d < 4; ++d) {
            float rz1 = params[(d * 4 + q) * 3 + 0];
            float ry  = params[(d * 4 + q) * 3 + 1];
            float rz2 = params[(d * 4 + q) * 3 + 2];
            float c  = __cosf(0.5f * ry),  s  = __sinf(0.5f * ry);
            c2 ph1  = { __cosf(0.5f * rz1), -__sinf(0.5f * rz1) };
            c2 ph1c = { ph1.re, -ph1.im };
            c2 ph2  = { __cosf(0.5f * rz2), -__sinf(0.5f * rz2) };
            c2 ph2c = { ph2.re, -ph2.im };
            c2 d00 = cmul(ph2,  { c * ph1.re,  c * ph1.im });
            c2 d01 = cmul(ph2,  {-s * ph1c.re, -s * ph1c.im});
            c2 d10 = cmul(ph2c, { s * ph1.re,  s * ph1.im });
            c2 d11 = cmul(ph2c, { c * ph1c.re, c * ph1c.im});
            c2 n00 = cadd(cmul(d00, m00), cmul(d01, m10));
            c2 n01 = cadd(cmul(d00, m01), cmul(d01, m11));
            c2 n10 = cadd(cmul(d10, m00), cmul(d11, m10));
            c2 n11 = cadd(cmul(d10, m01), cmul(d11, m11));
            m00 = n00; m01 = n01; m10 = n10; m11 = n11;
        }
        float n00 = m00.re*m00.re + m00.im*m00.im;
        float n10 = m10.re*m10.re + m10.im*m10.im;
        float n01 = m01.re*m01.re + m01.im*m01.im;
        float n11 = m11.re*m11.re + m11.im*m11.im;
        Aq[q] = 0.5f * (n00 - n10 - n01 + n11);
        Bq[q] = (m00.re*m01.re + m00.im*m01.im) - (m10.re*m11.re + m10.im*m11.im);
    }
}

// K0: build SoA table, one block per slot. 12 blocks x 256 threads.
__global__ __launch_bounds__(256) void k0_table(
    const float* __restrict__ params, const float* __restrict__ w,
    float4* __restrict__ tab4)
{
    int slot = blockIdx.x;          // 0=alpha, 1=beta, 2..11 = class slot-2
    int c    = threadIdx.x;         // chunk
    float Aq[4], Bq[4];
    if (slot < 2) su2_alpha_beta(params, Aq, Bq);
    float v[4];
    #pragma unroll
    for (int e = 0; e < 4; ++e) {
        int m = c * 4 + e;
        float val = 0.f;
        if (m < 784) {
            int r = m / 28, col = m - 28 * r;
            int q = ((r & 1) << 1) | (col & 1);
            if (slot == 0)      val = Aq[q];
            else if (slot == 1) val = Bq[q];
            else {
                int f = ((r >> 1) * 14 + (col >> 1)) * 4 + q;
                val = w[(slot - 2) * 784 + f];
            }
        }
        v[e] = val;
    }
    tab4[slot * NCH + c] = make_float4(v[0], v[1], v[2], v[3]);
}

// Main: 256 threads = 4 waves, 4 samples/wave -> 16 samples/block.
// lane = chunk stripe; 4 iterations cover 256 chunks. All LDS reads are
// lane-consecutive b128 -> conflict-free.
__global__ __launch_bounds__(256) void k_main(
    const float* __restrict__ x, const float4* __restrict__ tab4,
    const float* __restrict__ bias, float* __restrict__ out, int Bn)
{
    __shared__ __align__(16) float4 lds4[12 * NCH];   // 48 KiB
    __shared__ float wls[4][40];

    const int tid  = threadIdx.x;
    const int lane = tid & 63;
    const int wid  = tid >> 6;

    // coalesced table copy: 3072 float4 / 256 threads = 12 each
    #pragma unroll
    for (int k = 0; k < 12; ++k) lds4[tid + 256 * k] = tab4[tid + 256 * k];
    __syncthreads();

    const float4* x4 = (const float4*)x;
    int b0 = blockIdx.x * 16 + wid * 4;
    size_t xb[4];
    #pragma unroll
    for (int s = 0; s < 4; ++s) {
        int bs = b0 + s; if (bs > Bn - 1) bs = Bn - 1;
        xb[s] = (size_t)bs * 196;
    }

    float acc[4][10];
    #pragma unroll
    for (int s = 0; s < 4; ++s)
        #pragma unroll
        for (int cl = 0; cl < 10; ++cl) acc[s][cl] = 0.f;

    #pragma unroll
    for (int it = 0; it < 4; ++it) {
        int c  = it * 64 + lane;
        int cx = c < 196 ? c : 195;       // pad chunks: table is zero; clamp x index
        float4 xv[4];
        #pragma unroll
        for (int s = 0; s < 4; ++s) xv[s] = x4[xb[s] + cx];
        float4 al = lds4[c];
        float4 be = lds4[NCH + c];
        float z[4][4];
        #pragma unroll
        for (int s = 0; s < 4; ++s) {
            z[s][0] = fmaf(al.x, __cosf(xv[s].x), be.x * __sinf(xv[s].x));
            z[s][1] = fmaf(al.y, __cosf(xv[s].y), be.y * __sinf(xv[s].y));
            z[s][2] = fmaf(al.z, __cosf(xv[s].z), be.z * __sinf(xv[s].z));
            z[s][3] = fmaf(al.w, __cosf(xv[s].w), be.w * __sinf(xv[s].w));
        }
        #pragma unroll
        for (int cl = 0; cl < 10; ++cl) {
            float4 wv = lds4[(2 + cl) * NCH + c];
            #pragma unroll
            for (int s = 0; s < 4; ++s) {
                acc[s][cl] = fmaf(z[s][0], wv.x, acc[s][cl]);
                acc[s][cl] = fmaf(z[s][1], wv.y, acc[s][cl]);
                acc[s][cl] = fmaf(z[s][2], wv.z, acc[s][cl]);
                acc[s][cl] = fmaf(z[s][3], wv.w, acc[s][cl]);
            }
        }
    }

    // wave butterfly reduction over the 64 chunk-lanes
    #pragma unroll
    for (int s = 0; s < 4; ++s) {
        #pragma unroll
        for (int cl = 0; cl < 10; ++cl) {
            float v = acc[s][cl];
            v += __shfl_xor(v, 32, 64);
            v += __shfl_xor(v, 16, 64);
            v += __shfl_xor(v,  8, 64);
            v += __shfl_xor(v,  4, 64);
            v += __shfl_xor(v,  2, 64);
            v += __shfl_xor(v,  1, 64);
            if (lane == 0) wls[wid][s * 10 + cl] = v;
        }
    }
    __syncthreads();

    // log_softmax epilogue: lanes 0..39, one (sample, class) each
    if (lane < 40) {
        int s = lane / 10, cl = lane - 10 * s;
        const float* L = &wls[wid][s * 10];
        float mx = -1e30f;
        #pragma unroll
        for (int k = 0; k < 10; ++k) { float v = L[k] + bias[k]; mx = fmaxf(mx, v); }
        float sum = 0.f;
        #pragma unroll
        for (int k = 0; k < 10; ++k) sum += __expf(L[k] + bias[k] - mx);
        float lse = mx + __logf(sum);
        int b = b0 + s;
        if (b < Bn) out[b * 10 + cl] = (L[cl] + bias[cl]) - lse;
    }
}

extern "C" void kernel_launch(void* const* d_in, const int* in_sizes, int n_in,
                              void* d_out, int out_size, void* d_ws, size_t ws_size,
                              hipStream_t stream) {
    const float* x      = (const float*)d_in[0];
    const float* params = (const float*)d_in[1];
    const float* w      = (const float*)d_in[2];
    const float* bias   = (const float*)d_in[3];
    float* out = (float*)d_out;
    int Bn = in_sizes[0] / 784;

    float4* tab4 = (float4*)d_ws;   // 12*256*16 = 49152 B

    k0_table<<<12, 256, 0, stream>>>(params, w, tab4);
    k_main<<<(Bn + 15) / 16, 256, 0, stream>>>(x, tab4, bias, out, Bn);
}